// Round 7
// baseline (199.967 us; speedup 1.0000x reference)
//
#include <hip/hip_runtime.h>

#define NB 1024
#define NE 8

__device__ __forceinline__ float relu6f(float v) { return fminf(fmaxf(v, 0.0f), 6.0f); }

// ---------------- Kernel A: router conv + softmax ----------------
__global__ __launch_bounds__(256) void router_kernel(
    const float* __restrict__ x, const float* __restrict__ rw,
    const float* __restrict__ rb, float* __restrict__ ss)
{
    __shared__ float rw_l[384];
    __shared__ float red[4][8];
    int b = blockIdx.x, t = threadIdx.x;
    for (int i = t; i < 384; i += 256) rw_l[i] = rw[i];
    __syncthreads();
    float acc[NE];
#pragma unroll
    for (int e = 0; e < NE; ++e) acc[e] = 0.f;
    const float* xb = x + b * 3072;
    for (int idx = t; idx < 3072; idx += 256) {
        float xv = xb[idx];
        int c = idx >> 10, rem = idx & 1023;
        int i = rem >> 5, j = rem & 31;
        int wb = c * 16 + (i & 3) * 4 + (j & 3);
#pragma unroll
        for (int e = 0; e < NE; ++e) acc[e] += xv * rw_l[e * 48 + wb];
    }
#pragma unroll
    for (int off = 32; off >= 1; off >>= 1) {
#pragma unroll
        for (int e = 0; e < NE; ++e) acc[e] += __shfl_xor(acc[e], off);
    }
    int lane = t & 63, wave = t >> 6;
    if (lane == 0) {
#pragma unroll
        for (int e = 0; e < NE; ++e) red[wave][e] = acc[e];
    }
    __syncthreads();
    if (t == 0) {
        float s[NE], m = -1e30f;
#pragma unroll
        for (int e = 0; e < NE; ++e) {
            s[e] = red[0][e] + red[1][e] + red[2][e] + red[3][e] + rb[e];
            m = fmaxf(m, s[e]);
        }
        float xs = 0.f, ex[NE];
#pragma unroll
        for (int e = 0; e < NE; ++e) { ex[e] = expf(s[e] - m); xs += ex[e]; }
#pragma unroll
        for (int e = 0; e < NE; ++e) ss[b * 8 + e] = ex[e] / xs;
    }
}

// ---------------- Kernel B: OT solver — 4 waves, LDS-resident cost ---------
// Round-6 lesson: VGPR_Count=60 -> allocator targeted 8 waves/EU and spilled
// the ~100-float state. Two fixes: (a) __launch_bounds__(256,2) -> 256-reg
// budget; (b) drop c[4][8] from registers: ss lives transposed in LDS
// (sst[e][col], conflict-free) and ce = fma(ss, -inv0, -pi) on the fly.
// Live state ~60 floats -> no spill even at a pessimistic target.
// G_n = I8; G_m == I (off-diag d~5400 -> exp underflows), so C_eff = C - pi.
__global__ __launch_bounds__(256, 2) void solver_kernel(
    const float* __restrict__ ss_g, float* __restrict__ gate_ws,
    int* __restrict__ idx_ws, float* __restrict__ sel0,
    float* __restrict__ loss_out, float* __restrict__ mcnt_out)
{
    __shared__ float sst[8192];          // ss TRANSPOSED: sst[e*1024 + col]
    __shared__ float red[2][4][8];       // [parity][wave][e] row-sum partials
    __shared__ float redm[2][4];         // [parity][wave] max partials
    __shared__ float cnt_sh[4][8], dp_sh[4][8];

    int t = threadIdx.x;
    int l = t & 63, w = t >> 6;

    // stage ss -> transposed LDS (coalesced global float4), fold global max
    float mx = 0.f;
    for (int i = t; i < 2048; i += 256) {
        float4 s4 = ((const float4*)ss_g)[i];
        int col = i >> 1, e0 = (i & 1) * 4;
        sst[(e0 + 0) * 1024 + col] = s4.x;
        sst[(e0 + 1) * 1024 + col] = s4.y;
        sst[(e0 + 2) * 1024 + col] = s4.z;
        sst[(e0 + 3) * 1024 + col] = s4.w;
        mx = fmaxf(mx, fmaxf(fmaxf(s4.x, s4.y), fmaxf(s4.z, s4.w)));
    }
#pragma unroll
    for (int off = 32; off >= 1; off >>= 1) mx = fmaxf(mx, __shfl_xor(mx, off));
    if (l == 0) redm[0][w] = mx;
    __syncthreads();
    float gm = fmaxf(fmaxf(redm[0][0], redm[0][1]), fmaxf(redm[0][2], redm[0][3]));
    float ninv0 = -__builtin_amdgcn_rcpf(gm + 1e-9f);   // c = ss * ninv0

    // lane state: columns col = w*256 + q*64 + l, q in [0,4)
    int col0 = w * 256 + l;
    float k[4][8], v[4], u[8];
#pragma unroll
    for (int q = 0; q < 4; ++q) {
        v[q] = 1.f;
#pragma unroll
        for (int e = 0; e < 8; ++e) k[q][e] = 1.f;
    }
#pragma unroll
    for (int e = 0; e < 8; ++e) u[e] = 0.125f;   // u*k*v == pi0 == 0.125

    for (int outer = 0; outer < 25; ++outer) {
        int sm = (outer + 1) & 1;
        // ce = c - pi = fma(ss, ninv0, -u*k*v); store ce into k; track max|ce|
        float lm = 0.f;
#pragma unroll
        for (int q = 0; q < 4; ++q)
#pragma unroll
            for (int e = 0; e < 8; ++e) {
                float pi = u[e] * k[q][e] * v[q];
                float ssv = sst[e * 1024 + col0 + q * 64];
                float ce = fmaf(ssv, ninv0, -pi);
                k[q][e] = ce;
                lm = fmaxf(lm, fabsf(ce));
            }
#pragma unroll
        for (int off = 32; off >= 1; off >>= 1) lm = fmaxf(lm, __shfl_xor(lm, off));
        if (l == 0) redm[sm][w] = lm;
        __syncthreads();
        float gmx = fmaxf(fmaxf(redm[sm][0], redm[sm][1]),
                          fmaxf(redm[sm][2], redm[sm][3]));
        float scl = -10.f * __builtin_amdgcn_rcpf(gmx + 1e-9f);  // -(1/sden)/LDA
#pragma unroll
        for (int q = 0; q < 4; ++q) {
#pragma unroll
            for (int e = 0; e < 8; ++e) k[q][e] = __expf(k[q][e] * scl);
            v[q] = 1.f;
        }

        for (int it = 0; it < 6; ++it) {          // 5 full (u,v) + final u
            int s = it & 1;
            float p[8];
#pragma unroll
            for (int e = 0; e < 8; ++e) p[e] = 0.f;
#pragma unroll
            for (int q = 0; q < 4; ++q)
#pragma unroll
                for (int e = 0; e < 8; ++e) p[e] = fmaf(k[q][e], v[q], p[e]);
#pragma unroll
            for (int off = 32; off >= 1; off >>= 1) {
#pragma unroll
                for (int e = 0; e < 8; ++e) p[e] += __shfl_xor(p[e], off);
            }
            if (l == 0) {
#pragma unroll
                for (int e = 0; e < 8; ++e) red[s][w][e] = p[e];
            }
            __syncthreads();
#pragma unroll
            for (int e = 0; e < 8; ++e) {
                float tot = red[s][0][e] + red[s][1][e] + red[s][2][e] + red[s][3][e];
                u[e] = 128.f * __builtin_amdgcn_rcpf(tot + 1e-9f);
            }
            if (it < 5) {
#pragma unroll
                for (int q = 0; q < 4; ++q) {
                    float cs = 0.f;
#pragma unroll
                    for (int e = 0; e < 8; ++e) cs = fmaf(k[q][e], u[e], cs);
                    v[q] = __builtin_amdgcn_rcpf(cs + 1e-9f);
                }
            }
        }
    }

    // ---- epilogue: argmax / gate / select0 / counts / loss ----
    float cnt[8], dp[8];
#pragma unroll
    for (int e = 0; e < 8; ++e) { cnt[e] = 0.f; dp[e] = 0.f; }
#pragma unroll
    for (int q = 0; q < 4; ++q) {
        int col = col0 + q * 64;
        float pv[8];
#pragma unroll
        for (int e = 0; e < 8; ++e) pv[e] = u[e] * k[q][e] * v[q];
        int i = 0; float m = pv[0];
#pragma unroll
        for (int e = 1; e < 8; ++e) { if (pv[e] > m) { m = pv[e]; i = e; } }
        float g = 0.f;
        float se[8];
#pragma unroll
        for (int e = 0; e < 8; ++e) {
            float sv = sst[e * 1024 + col];
            dp[e] += sv;
            if (i == e) g = sv;
        }
#pragma unroll
        for (int e = 0; e < 8; ++e) {
            se[e] = (e == i && g != 0.f) ? 1.f : 0.f;
            cnt[e] += (e == i) ? 1.f : 0.f;
        }
        idx_ws[col] = i;
        gate_ws[col] = g;
        *(float4*)&sel0[col * 8]     = make_float4(se[0], se[1], se[2], se[3]);
        *(float4*)&sel0[col * 8 + 4] = make_float4(se[4], se[5], se[6], se[7]);
    }
#pragma unroll
    for (int off = 32; off >= 1; off >>= 1) {
#pragma unroll
        for (int e = 0; e < 8; ++e) {
            cnt[e] += __shfl_xor(cnt[e], off);
            dp[e]  += __shfl_xor(dp[e], off);
        }
    }
    if (l == 0) {
#pragma unroll
        for (int e = 0; e < 8; ++e) { cnt_sh[w][e] = cnt[e]; dp_sh[w][e] = dp[e]; }
    }
    __syncthreads();
    if (t == 0) {
        float loss = 0.f;
#pragma unroll
        for (int e = 0; e < 8; ++e) {
            float ce2 = cnt_sh[0][e] + cnt_sh[1][e] + cnt_sh[2][e] + cnt_sh[3][e];
            float de2 = dp_sh[0][e] + dp_sh[1][e] + dp_sh[2][e] + dp_sh[3][e];
            loss += (de2 * (1.f / 1024.f)) * (ce2 * (1.f / 1024.f));
            mcnt_out[e] = ce2;
        }
        loss_out[0] = loss * 8.f;       // mean over 8 * E^2=64 -> sum * 8
    }
}

// ---------------- Kernel C: per-sample fused expert forward ----------------
__global__ __launch_bounds__(256) void expert_kernel(
    const float* __restrict__ x,
    const float* __restrict__ w1g, const float* __restrict__ b1g,
    const float* __restrict__ wdg, const float* __restrict__ bdg,
    const float* __restrict__ wpg, const float* __restrict__ bpg,
    const float* __restrict__ wfg, const float* __restrict__ bfg,
    const int* __restrict__ idx_ws, const float* __restrict__ gate_ws,
    float* __restrict__ out)
{
    __shared__ float xl[3][34][35];
    __shared__ float h1[4][33][33];
    __shared__ float h2[16][16][17];
    __shared__ float w1_l[432];
    __shared__ float wd_l[144];
    __shared__ float wp_l[512];
    __shared__ float wf_l[320];
    __shared__ float b1_l[16], bd_l[16], bp_l[32], bf_l[10];
    __shared__ float poolp[32][9];
    __shared__ float pooled[32];

    int b = blockIdx.x, t = threadIdx.x;
    int e = idx_ws[b];
    float gate = gate_ws[b];

    float* xz = &xl[0][0][0];
    for (int i = t; i < 3 * 34 * 35; i += 256) xz[i] = 0.f;
    for (int i = t; i < 432; i += 256) w1_l[i] = w1g[e * 432 + i];
    if (t < 144) wd_l[t] = wdg[e * 144 + t];
    for (int i = t; i < 512; i += 256) wp_l[i] = wpg[e * 512 + i];
    for (int i = t; i < 320; i += 256) wf_l[i] = wfg[e * 320 + i];
    if (t < 16) b1_l[t] = b1g[e * 16 + t];
    if (t < 16) bd_l[t] = bdg[e * 16 + t];
    if (t < 32) bp_l[t] = bpg[e * 32 + t];
    if (t < 10) bf_l[t] = bfg[e * 10 + t];
    __syncthreads();
    const float* xb = x + b * 3072;
    for (int i = t; i < 3072; i += 256) {
        int c = i >> 10, r = (i >> 5) & 31, j = i & 31;
        xl[c][r + 1][j + 1] = xb[i];
    }
    __syncthreads();

    int ocl = t >> 6;
    int rr = (t >> 1) & 31;
    int jh = t & 1;

    for (int g = 0; g < 4; ++g) {
        int oc = g * 4 + ocl;
        float acc[16];
        float bb = b1_l[oc];
#pragma unroll
        for (int kk = 0; kk < 16; ++kk) acc[kk] = bb;
#pragma unroll
        for (int c = 0; c < 3; ++c) {
#pragma unroll
            for (int di = 0; di < 3; ++di) {
                const float* xr = &xl[c][rr + di][jh * 16];
                float xreg[18];
#pragma unroll
                for (int kk = 0; kk < 18; ++kk) xreg[kk] = xr[kk];
#pragma unroll
                for (int dj = 0; dj < 3; ++dj) {
                    float w = w1_l[oc * 27 + c * 9 + di * 3 + dj];
#pragma unroll
                    for (int kk = 0; kk < 16; ++kk) acc[kk] = fmaf(xreg[kk + dj], w, acc[kk]);
                }
            }
        }
#pragma unroll
        for (int kk = 0; kk < 16; ++kk) h1[ocl][rr][jh * 16 + kk] = relu6f(acc[kk]);
        if (t < 132) { int cc = t / 33, kk = t % 33; h1[cc][32][kk] = 0.f; }
        if (t < 128) { h1[t >> 5][t & 31][32] = 0.f; }
        __syncthreads();
        int i2 = t >> 4, j2 = t & 15;
#pragma unroll
        for (int q = 0; q < 4; ++q) {
            float a = bd_l[g * 4 + q];
#pragma unroll
            for (int di = 0; di < 3; ++di) {
#pragma unroll
                for (int dj = 0; dj < 3; ++dj)
                    a = fmaf(h1[q][2 * i2 + di][2 * j2 + dj],
                             wd_l[(g * 4 + q) * 9 + di * 3 + dj], a);
            }
            h2[g * 4 + q][i2][j2] = relu6f(a);
        }
        __syncthreads();
    }

    int oc2 = t >> 3, part = t & 7;
    float psum = 0.f;
#pragma unroll
    for (int s = 0; s < 32; ++s) {
        int p = part * 32 + s;
        int i = p >> 4, j = p & 15;
        float a = bp_l[oc2];
#pragma unroll
        for (int c = 0; c < 16; ++c) a = fmaf(h2[c][i][j], wp_l[oc2 * 16 + c], a);
        psum += relu6f(a);
    }
    poolp[oc2][part] = psum;
    __syncthreads();
    if (t < 32) {
        float s2 = 0.f;
#pragma unroll
        for (int p2 = 0; p2 < 8; ++p2) s2 += poolp[t][p2];
        pooled[t] = s2 * (1.0f / 256.0f);
    }
    __syncthreads();
    if (t < 10) {
        float o = bf_l[t];
#pragma unroll
        for (int c = 0; c < 32; ++c) o = fmaf(pooled[c], wf_l[t * 32 + c], o);
        out[b * 10 + t] = gate * o;
    }
}

extern "C" void kernel_launch(void* const* d_in, const int* in_sizes, int n_in,
                              void* d_out, int out_size, void* d_ws, size_t ws_size,
                              hipStream_t stream) {
    const float* x  = (const float*)d_in[0];
    const float* rw = (const float*)d_in[1];
    const float* rb = (const float*)d_in[2];
    const float* w1 = (const float*)d_in[3];
    const float* b1 = (const float*)d_in[4];
    const float* wd = (const float*)d_in[5];
    const float* bd = (const float*)d_in[6];
    const float* wp = (const float*)d_in[7];
    const float* bp = (const float*)d_in[8];
    const float* wf = (const float*)d_in[9];
    const float* bf = (const float*)d_in[10];

    float* out  = (float*)d_out;       // [1024*10]
    float* sel0 = out + 10240;         // [1024*8]
    float* loss = out + 18432;         // [1]
    float* mcnt = out + 18433;         // [8]

    float* ws_f = (float*)d_ws;
    float* ss   = ws_f;                 // 8192 floats
    float* gate = ws_f + 8192;          // 1024 floats
    int*   idx  = (int*)(ws_f + 9216);  // 1024 ints

    router_kernel<<<dim3(NB), dim3(256), 0, stream>>>(x, rw, rb, ss);
    solver_kernel<<<dim3(1), dim3(256), 0, stream>>>(ss, gate, idx, sel0, loss, mcnt);
    expert_kernel<<<dim3(NB), dim3(256), 0, stream>>>(x, w1, b1, wd, bd, wp, bp,
                                                      wf, bf, idx, gate, out);
}

// Round 8
// 175.599 us; speedup vs baseline: 1.1388x; 1.1388x over previous
//
#include <hip/hip_runtime.h>

#define NB 1024
#define NE 8

__device__ __forceinline__ float relu6f(float v) { return fminf(fmaxf(v, 0.0f), 6.0f); }

// ---- DPP-based wave64 reductions (result in ALL lanes) ----
// row_ror:1/2/4/8 reduce within 16-lane rows on the VALU pipe (low latency),
// ds_swizzle xor16 combines rows within each 32-half, shfl_xor(32) crosses halves.
template <int CTRL>
__device__ __forceinline__ float dpp_mv(float x) {
    return __builtin_bit_cast(float,
        __builtin_amdgcn_update_dpp(0, __builtin_bit_cast(int, x), CTRL, 0xF, 0xF, false));
}
__device__ __forceinline__ float wred_add(float x) {
    x += dpp_mv<0x121>(x);   // row_ror:1
    x += dpp_mv<0x122>(x);   // row_ror:2
    x += dpp_mv<0x124>(x);   // row_ror:4
    x += dpp_mv<0x128>(x);   // row_ror:8
    x += __builtin_bit_cast(float,
        __builtin_amdgcn_ds_swizzle(__builtin_bit_cast(int, x), 0x401F)); // xor16
    x += __shfl_xor(x, 32);
    return x;
}
__device__ __forceinline__ float wred_max(float x) {
    x = fmaxf(x, dpp_mv<0x121>(x));
    x = fmaxf(x, dpp_mv<0x122>(x));
    x = fmaxf(x, dpp_mv<0x124>(x));
    x = fmaxf(x, dpp_mv<0x128>(x));
    x = fmaxf(x, __builtin_bit_cast(float,
        __builtin_amdgcn_ds_swizzle(__builtin_bit_cast(int, x), 0x401F)));
    x = fmaxf(x, __shfl_xor(x, 32));
    return x;
}

// ---------------- Kernel A: router conv + softmax ----------------
__global__ __launch_bounds__(256) void router_kernel(
    const float* __restrict__ x, const float* __restrict__ rw,
    const float* __restrict__ rb, float* __restrict__ ss)
{
    __shared__ float rw_l[384];
    __shared__ float red[4][8];
    int b = blockIdx.x, t = threadIdx.x;
    for (int i = t; i < 384; i += 256) rw_l[i] = rw[i];
    __syncthreads();
    float acc[NE];
#pragma unroll
    for (int e = 0; e < NE; ++e) acc[e] = 0.f;
    const float* xb = x + b * 3072;
    for (int idx = t; idx < 3072; idx += 256) {
        float xv = xb[idx];
        int c = idx >> 10, rem = idx & 1023;
        int i = rem >> 5, j = rem & 31;
        int wb = c * 16 + (i & 3) * 4 + (j & 3);
#pragma unroll
        for (int e = 0; e < NE; ++e) acc[e] += xv * rw_l[e * 48 + wb];
    }
#pragma unroll
    for (int e = 0; e < NE; ++e) acc[e] = wred_add(acc[e]);
    int lane = t & 63, wave = t >> 6;
    if (lane == 0) {
#pragma unroll
        for (int e = 0; e < NE; ++e) red[wave][e] = acc[e];
    }
    __syncthreads();
    if (t == 0) {
        float s[NE], m = -1e30f;
#pragma unroll
        for (int e = 0; e < NE; ++e) {
            s[e] = red[0][e] + red[1][e] + red[2][e] + red[3][e] + rb[e];
            m = fmaxf(m, s[e]);
        }
        float xs = 0.f, ex[NE];
#pragma unroll
        for (int e = 0; e < NE; ++e) { ex[e] = expf(s[e] - m); xs += ex[e]; }
#pragma unroll
        for (int e = 0; e < NE; ++e) ss[b * 8 + e] = ex[e] / xs;
    }
}

// ---------------- Kernel B: OT solver — 4 waves, DPP reduce ----------------
// Round-7 lesson: bottleneck is the LATENCY of the per-step reduce chain
// (6 dependent shfl rounds + barrier + 32 scalar LDS reads), not spill.
// This round: DPP row_ror reduce (~90cy chain), float4 partial read-back.
// G_n = I8; G_m == I (off-diag d~5400 -> exp underflows), so C_eff = C - pi.
__global__ __launch_bounds__(256, 2) void solver_kernel(
    const float* __restrict__ ss_g, float* __restrict__ gate_ws,
    int* __restrict__ idx_ws, float* __restrict__ sel0,
    float* __restrict__ loss_out, float* __restrict__ mcnt_out)
{
    __shared__ float sst[8192];                      // ss transposed: [e*1024+col]
    __shared__ __align__(16) float red[2][4][8];     // [parity][wave][e]
    __shared__ float redm[2][4];                     // [parity][wave] max partials
    __shared__ float cnt_sh[4][8], dp_sh[4][8];

    int t = threadIdx.x;
    int l = t & 63, w = t >> 6;

    // stage ss -> transposed LDS, fold global max (ss > 0)
    float mx = 0.f;
    for (int i = t; i < 2048; i += 256) {
        float4 s4 = ((const float4*)ss_g)[i];
        int col = i >> 1, e0 = (i & 1) * 4;
        sst[(e0 + 0) * 1024 + col] = s4.x;
        sst[(e0 + 1) * 1024 + col] = s4.y;
        sst[(e0 + 2) * 1024 + col] = s4.z;
        sst[(e0 + 3) * 1024 + col] = s4.w;
        mx = fmaxf(mx, fmaxf(fmaxf(s4.x, s4.y), fmaxf(s4.z, s4.w)));
    }
    mx = wred_max(mx);
    if (l == 0) redm[0][w] = mx;
    __syncthreads();
    float gm = fmaxf(fmaxf(redm[0][0], redm[0][1]), fmaxf(redm[0][2], redm[0][3]));
    float ninv0 = -__builtin_amdgcn_rcpf(gm + 1e-9f);   // c = ss * ninv0

    // lane state: columns col = w*256 + q*64 + l, q in [0,4)
    int col0 = w * 256 + l;
    float k[4][8], v[4], u[8];
#pragma unroll
    for (int q = 0; q < 4; ++q) {
        v[q] = 1.f;
#pragma unroll
        for (int e = 0; e < 8; ++e) k[q][e] = 1.f;
    }
#pragma unroll
    for (int e = 0; e < 8; ++e) u[e] = 0.125f;   // u*k*v == pi0 == 0.125

    for (int outer = 0; outer < 25; ++outer) {
        int sm = (outer + 1) & 1;
        // ce = c - pi = fma(ss, ninv0, -u*k*v); store ce into k; track max|ce|
        float lm = 0.f;
#pragma unroll
        for (int q = 0; q < 4; ++q)
#pragma unroll
            for (int e = 0; e < 8; ++e) {
                float pi = u[e] * k[q][e] * v[q];
                float ssv = sst[e * 1024 + col0 + q * 64];
                float ce = fmaf(ssv, ninv0, -pi);
                k[q][e] = ce;
                lm = fmaxf(lm, fabsf(ce));
            }
        lm = wred_max(lm);
        if (l == 0) redm[sm][w] = lm;
        __syncthreads();
        float gmx = fmaxf(fmaxf(redm[sm][0], redm[sm][1]),
                          fmaxf(redm[sm][2], redm[sm][3]));
        float scl = -10.f * __builtin_amdgcn_rcpf(gmx + 1e-9f);  // -(1/sden)/LDA
#pragma unroll
        for (int q = 0; q < 4; ++q) {
#pragma unroll
            for (int e = 0; e < 8; ++e) k[q][e] = __expf(k[q][e] * scl);
            v[q] = 1.f;
        }

        for (int it = 0; it < 6; ++it) {          // 5 full (u,v) + final u
            int s = it & 1;
            float p[8];
#pragma unroll
            for (int e = 0; e < 8; ++e) p[e] = 0.f;
#pragma unroll
            for (int q = 0; q < 4; ++q)
#pragma unroll
                for (int e = 0; e < 8; ++e) p[e] = fmaf(k[q][e], v[q], p[e]);
#pragma unroll
            for (int e = 0; e < 8; ++e) p[e] = wred_add(p[e]);
            if (l == 0) {
#pragma unroll
                for (int e = 0; e < 8; ++e) red[s][w][e] = p[e];
            }
            __syncthreads();
            // combine 4 wave-partials: 8 aligned float4 broadcast loads
            float4 t00 = *(const float4*)&red[s][0][0];
            float4 t01 = *(const float4*)&red[s][0][4];
            float4 t10 = *(const float4*)&red[s][1][0];
            float4 t11 = *(const float4*)&red[s][1][4];
            float4 t20 = *(const float4*)&red[s][2][0];
            float4 t21 = *(const float4*)&red[s][2][4];
            float4 t30 = *(const float4*)&red[s][3][0];
            float4 t31 = *(const float4*)&red[s][3][4];
            float tot0x = (t00.x + t10.x) + (t20.x + t30.x);
            float tot0y = (t00.y + t10.y) + (t20.y + t30.y);
            float tot0z = (t00.z + t10.z) + (t20.z + t30.z);
            float tot0w = (t00.w + t10.w) + (t20.w + t30.w);
            float tot1x = (t01.x + t11.x) + (t21.x + t31.x);
            float tot1y = (t01.y + t11.y) + (t21.y + t31.y);
            float tot1z = (t01.z + t11.z) + (t21.z + t31.z);
            float tot1w = (t01.w + t11.w) + (t21.w + t31.w);
            u[0] = 128.f * __builtin_amdgcn_rcpf(tot0x + 1e-9f);
            u[1] = 128.f * __builtin_amdgcn_rcpf(tot0y + 1e-9f);
            u[2] = 128.f * __builtin_amdgcn_rcpf(tot0z + 1e-9f);
            u[3] = 128.f * __builtin_amdgcn_rcpf(tot0w + 1e-9f);
            u[4] = 128.f * __builtin_amdgcn_rcpf(tot1x + 1e-9f);
            u[5] = 128.f * __builtin_amdgcn_rcpf(tot1y + 1e-9f);
            u[6] = 128.f * __builtin_amdgcn_rcpf(tot1z + 1e-9f);
            u[7] = 128.f * __builtin_amdgcn_rcpf(tot1w + 1e-9f);
            if (it < 5) {
#pragma unroll
                for (int q = 0; q < 4; ++q) {
                    float cs = 0.f;
#pragma unroll
                    for (int e = 0; e < 8; ++e) cs = fmaf(k[q][e], u[e], cs);
                    v[q] = __builtin_amdgcn_rcpf(cs + 1e-9f);
                }
            }
        }
    }

    // ---- epilogue: argmax / gate / select0 / counts / loss ----
    float cnt[8], dp[8];
#pragma unroll
    for (int e = 0; e < 8; ++e) { cnt[e] = 0.f; dp[e] = 0.f; }
#pragma unroll
    for (int q = 0; q < 4; ++q) {
        int col = col0 + q * 64;
        float pv[8];
#pragma unroll
        for (int e = 0; e < 8; ++e) pv[e] = u[e] * k[q][e] * v[q];
        int i = 0; float m = pv[0];
#pragma unroll
        for (int e = 1; e < 8; ++e) { if (pv[e] > m) { m = pv[e]; i = e; } }
        float g = 0.f;
        float se[8];
#pragma unroll
        for (int e = 0; e < 8; ++e) {
            float sv = sst[e * 1024 + col];
            dp[e] += sv;
            if (i == e) g = sv;
        }
#pragma unroll
        for (int e = 0; e < 8; ++e) {
            se[e] = (e == i && g != 0.f) ? 1.f : 0.f;
            cnt[e] += (e == i) ? 1.f : 0.f;
        }
        idx_ws[col] = i;
        gate_ws[col] = g;
        *(float4*)&sel0[col * 8]     = make_float4(se[0], se[1], se[2], se[3]);
        *(float4*)&sel0[col * 8 + 4] = make_float4(se[4], se[5], se[6], se[7]);
    }
#pragma unroll
    for (int e = 0; e < 8; ++e) { cnt[e] = wred_add(cnt[e]); dp[e] = wred_add(dp[e]); }
    if (l == 0) {
#pragma unroll
        for (int e = 0; e < 8; ++e) { cnt_sh[w][e] = cnt[e]; dp_sh[w][e] = dp[e]; }
    }
    __syncthreads();
    if (t == 0) {
        float loss = 0.f;
#pragma unroll
        for (int e = 0; e < 8; ++e) {
            float ce2 = cnt_sh[0][e] + cnt_sh[1][e] + cnt_sh[2][e] + cnt_sh[3][e];
            float de2 = dp_sh[0][e] + dp_sh[1][e] + dp_sh[2][e] + dp_sh[3][e];
            loss += (de2 * (1.f / 1024.f)) * (ce2 * (1.f / 1024.f));
            mcnt_out[e] = ce2;
        }
        loss_out[0] = loss * 8.f;       // mean over 8 * E^2=64 -> sum * 8
    }
}

// ---------------- Kernel C: per-sample fused expert forward ----------------
__global__ __launch_bounds__(256) void expert_kernel(
    const float* __restrict__ x,
    const float* __restrict__ w1g, const float* __restrict__ b1g,
    const float* __restrict__ wdg, const float* __restrict__ bdg,
    const float* __restrict__ wpg, const float* __restrict__ bpg,
    const float* __restrict__ wfg, const float* __restrict__ bfg,
    const int* __restrict__ idx_ws, const float* __restrict__ gate_ws,
    float* __restrict__ out)
{
    __shared__ float xl[3][34][35];
    __shared__ float h1[4][33][33];
    __shared__ float h2[16][16][17];
    __shared__ float w1_l[432];
    __shared__ float wd_l[144];
    __shared__ float wp_l[512];
    __shared__ float wf_l[320];
    __shared__ float b1_l[16], bd_l[16], bp_l[32], bf_l[10];
    __shared__ float poolp[32][9];
    __shared__ float pooled[32];

    int b = blockIdx.x, t = threadIdx.x;
    int e = idx_ws[b];
    float gate = gate_ws[b];

    float* xz = &xl[0][0][0];
    for (int i = t; i < 3 * 34 * 35; i += 256) xz[i] = 0.f;
    for (int i = t; i < 432; i += 256) w1_l[i] = w1g[e * 432 + i];
    if (t < 144) wd_l[t] = wdg[e * 144 + t];
    for (int i = t; i < 512; i += 256) wp_l[i] = wpg[e * 512 + i];
    for (int i = t; i < 320; i += 256) wf_l[i] = wfg[e * 320 + i];
    if (t < 16) b1_l[t] = b1g[e * 16 + t];
    if (t < 16) bd_l[t] = bdg[e * 16 + t];
    if (t < 32) bp_l[t] = bpg[e * 32 + t];
    if (t < 10) bf_l[t] = bfg[e * 10 + t];
    __syncthreads();
    const float* xb = x + b * 3072;
    for (int i = t; i < 3072; i += 256) {
        int c = i >> 10, r = (i >> 5) & 31, j = i & 31;
        xl[c][r + 1][j + 1] = xb[i];
    }
    __syncthreads();

    int ocl = t >> 6;
    int rr = (t >> 1) & 31;
    int jh = t & 1;

    for (int g = 0; g < 4; ++g) {
        int oc = g * 4 + ocl;
        float acc[16];
        float bb = b1_l[oc];
#pragma unroll
        for (int kk = 0; kk < 16; ++kk) acc[kk] = bb;
#pragma unroll
        for (int c = 0; c < 3; ++c) {
#pragma unroll
            for (int di = 0; di < 3; ++di) {
                const float* xr = &xl[c][rr + di][jh * 16];
                float xreg[18];
#pragma unroll
                for (int kk = 0; kk < 18; ++kk) xreg[kk] = xr[kk];
#pragma unroll
                for (int dj = 0; dj < 3; ++dj) {
                    float w = w1_l[oc * 27 + c * 9 + di * 3 + dj];
#pragma unroll
                    for (int kk = 0; kk < 16; ++kk) acc[kk] = fmaf(xreg[kk + dj], w, acc[kk]);
                }
            }
        }
#pragma unroll
        for (int kk = 0; kk < 16; ++kk) h1[ocl][rr][jh * 16 + kk] = relu6f(acc[kk]);
        if (t < 132) { int cc = t / 33, kk = t % 33; h1[cc][32][kk] = 0.f; }
        if (t < 128) { h1[t >> 5][t & 31][32] = 0.f; }
        __syncthreads();
        int i2 = t >> 4, j2 = t & 15;
#pragma unroll
        for (int q = 0; q < 4; ++q) {
            float a = bd_l[g * 4 + q];
#pragma unroll
            for (int di = 0; di < 3; ++di) {
#pragma unroll
                for (int dj = 0; dj < 3; ++dj)
                    a = fmaf(h1[q][2 * i2 + di][2 * j2 + dj],
                             wd_l[(g * 4 + q) * 9 + di * 3 + dj], a);
            }
            h2[g * 4 + q][i2][j2] = relu6f(a);
        }
        __syncthreads();
    }

    int oc2 = t >> 3, part = t & 7;
    float psum = 0.f;
#pragma unroll
    for (int s = 0; s < 32; ++s) {
        int p = part * 32 + s;
        int i = p >> 4, j = p & 15;
        float a = bp_l[oc2];
#pragma unroll
        for (int c = 0; c < 16; ++c) a = fmaf(h2[c][i][j], wp_l[oc2 * 16 + c], a);
        psum += relu6f(a);
    }
    poolp[oc2][part] = psum;
    __syncthreads();
    if (t < 32) {
        float s2 = 0.f;
#pragma unroll
        for (int p2 = 0; p2 < 8; ++p2) s2 += poolp[t][p2];
        pooled[t] = s2 * (1.0f / 256.0f);
    }
    __syncthreads();
    if (t < 10) {
        float o = bf_l[t];
#pragma unroll
        for (int c = 0; c < 32; ++c) o = fmaf(pooled[c], wf_l[t * 32 + c], o);
        out[b * 10 + t] = gate * o;
    }
}

extern "C" void kernel_launch(void* const* d_in, const int* in_sizes, int n_in,
                              void* d_out, int out_size, void* d_ws, size_t ws_size,
                              hipStream_t stream) {
    const float* x  = (const float*)d_in[0];
    const float* rw = (const float*)d_in[1];
    const float* rb = (const float*)d_in[2];
    const float* w1 = (const float*)d_in[3];
    const float* b1 = (const float*)d_in[4];
    const float* wd = (const float*)d_in[5];
    const float* bd = (const float*)d_in[6];
    const float* wp = (const float*)d_in[7];
    const float* bp = (const float*)d_in[8];
    const float* wf = (const float*)d_in[9];
    const float* bf = (const float*)d_in[10];

    float* out  = (float*)d_out;       // [1024*10]
    float* sel0 = out + 10240;         // [1024*8]
    float* loss = out + 18432;         // [1]
    float* mcnt = out + 18433;         // [8]

    float* ws_f = (float*)d_ws;
    float* ss   = ws_f;                 // 8192 floats
    float* gate = ws_f + 8192;          // 1024 floats
    int*   idx  = (int*)(ws_f + 9216);  // 1024 ints

    router_kernel<<<dim3(NB), dim3(256), 0, stream>>>(x, rw, rb, ss);
    solver_kernel<<<dim3(1), dim3(256), 0, stream>>>(ss, gate, idx, sel0, loss, mcnt);
    expert_kernel<<<dim3(NB), dim3(256), 0, stream>>>(x, w1, b1, wd, bd, wp, bp,
                                                      wf, bf, idx, gate, out);
}

// Round 9
// 167.257 us; speedup vs baseline: 1.1956x; 1.0499x over previous
//
#include <hip/hip_runtime.h>

#define NB 1024
#define NE 8

__device__ __forceinline__ float relu6f(float v) { return fminf(fmaxf(v, 0.0f), 6.0f); }

// ---- pure-DPP wave64 reductions (GCN row_ror + row_bcast finisher) ----
// After row_ror 1/2/4/8 each lane holds its 16-lane row sum; row_bcast15 adds
// row0->row1 / row2->row3; row_bcast31 adds (row0+row1)->rows 2,3.
// Full 64-lane result is valid in lanes 48..63 ONLY. old=0 + bound_ctrl=false
// makes unselected lanes add 0 (safe for sum; safe for max of nonneg values).
template <int CTRL>
__device__ __forceinline__ float dpp0(float x) {
    return __builtin_bit_cast(float,
        __builtin_amdgcn_update_dpp(0, __builtin_bit_cast(int, x), CTRL, 0xF, 0xF, false));
}
__device__ __forceinline__ float wsum63(float x) {
    x += dpp0<0x121>(x);   // row_ror:1
    x += dpp0<0x122>(x);   // row_ror:2
    x += dpp0<0x124>(x);   // row_ror:4
    x += dpp0<0x128>(x);   // row_ror:8
    x += dpp0<0x142>(x);   // row_bcast:15
    x += dpp0<0x143>(x);   // row_bcast:31
    return x;
}
__device__ __forceinline__ float wmax63(float x) {   // nonneg inputs only
    x = fmaxf(x, dpp0<0x121>(x));
    x = fmaxf(x, dpp0<0x122>(x));
    x = fmaxf(x, dpp0<0x124>(x));
    x = fmaxf(x, dpp0<0x128>(x));
    x = fmaxf(x, dpp0<0x142>(x));
    x = fmaxf(x, dpp0<0x143>(x));
    return x;
}

// ---------------- Kernel A: router conv + softmax ----------------
__global__ __launch_bounds__(256) void router_kernel(
    const float* __restrict__ x, const float* __restrict__ rw,
    const float* __restrict__ rb, float* __restrict__ ss)
{
    __shared__ float rw_l[384];
    __shared__ float red[4][8];
    int b = blockIdx.x, t = threadIdx.x;
    for (int i = t; i < 384; i += 256) rw_l[i] = rw[i];
    __syncthreads();
    float acc[NE];
#pragma unroll
    for (int e = 0; e < NE; ++e) acc[e] = 0.f;
    const float* xb = x + b * 3072;
    for (int idx = t; idx < 3072; idx += 256) {
        float xv = xb[idx];
        int c = idx >> 10, rem = idx & 1023;
        int i = rem >> 5, j = rem & 31;
        int wb = c * 16 + (i & 3) * 4 + (j & 3);
#pragma unroll
        for (int e = 0; e < NE; ++e) acc[e] += xv * rw_l[e * 48 + wb];
    }
#pragma unroll
    for (int e = 0; e < NE; ++e) acc[e] = wsum63(acc[e]);
    int lane = t & 63, wave = t >> 6;
    if (lane == 63) {
#pragma unroll
        for (int e = 0; e < NE; ++e) red[wave][e] = acc[e];
    }
    __syncthreads();
    if (t == 0) {
        float s[NE], m = -1e30f;
#pragma unroll
        for (int e = 0; e < NE; ++e) {
            s[e] = red[0][e] + red[1][e] + red[2][e] + red[3][e] + rb[e];
            m = fmaxf(m, s[e]);
        }
        float xs = 0.f, ex[NE];
#pragma unroll
        for (int e = 0; e < NE; ++e) { ex[e] = expf(s[e] - m); xs += ex[e]; }
#pragma unroll
        for (int e = 0; e < NE; ++e) ss[b * 8 + e] = ex[e] / xs;
    }
}

// ---------------- Kernel B: OT solver — 4 waves, pure-DPP reduce -----------
// Per inner step: p-FMA -> 8x wsum63 (pure VALU) -> lane63 2x ds_write_b128
// -> barrier -> 8x broadcast b128 reads (deterministic fixed tree) -> rcp.
// G_n = I8; G_m == I (off-diag d~5400 -> exp underflows), so C_eff = C - pi.
__global__ __launch_bounds__(256, 2) void solver_kernel(
    const float* __restrict__ ss_g, float* __restrict__ gate_ws,
    int* __restrict__ idx_ws, float* __restrict__ sel0,
    float* __restrict__ loss_out, float* __restrict__ mcnt_out)
{
    __shared__ float sst[8192];                      // ss transposed: [e*1024+col]
    __shared__ __align__(16) float red[2][4][8];     // [parity][wave][e]
    __shared__ float redm[2][4];                     // [parity][wave] max partials
    __shared__ __align__(16) float cnt_sh[4][8], dp_sh[4][8];

    int t = threadIdx.x;
    int l = t & 63, w = t >> 6;

    // stage ss -> transposed LDS, fold global max (ss > 0)
    float mx = 0.f;
    for (int i = t; i < 2048; i += 256) {
        float4 s4 = ((const float4*)ss_g)[i];
        int col = i >> 1, e0 = (i & 1) * 4;
        sst[(e0 + 0) * 1024 + col] = s4.x;
        sst[(e0 + 1) * 1024 + col] = s4.y;
        sst[(e0 + 2) * 1024 + col] = s4.z;
        sst[(e0 + 3) * 1024 + col] = s4.w;
        mx = fmaxf(mx, fmaxf(fmaxf(s4.x, s4.y), fmaxf(s4.z, s4.w)));
    }
    mx = wmax63(mx);
    if (l == 63) redm[0][w] = mx;
    __syncthreads();
    float gm = fmaxf(fmaxf(redm[0][0], redm[0][1]), fmaxf(redm[0][2], redm[0][3]));
    float ninv0 = -__builtin_amdgcn_rcpf(gm + 1e-9f);   // c = ss * ninv0

    // lane state: columns col = w*256 + q*64 + l, q in [0,4)
    int col0 = w * 256 + l;
    float k[4][8], v[4], u[8];
#pragma unroll
    for (int q = 0; q < 4; ++q) {
        v[q] = 1.f;
#pragma unroll
        for (int e = 0; e < 8; ++e) k[q][e] = 1.f;
    }
#pragma unroll
    for (int e = 0; e < 8; ++e) u[e] = 0.125f;   // u*k*v == pi0 == 0.125

    for (int outer = 0; outer < 25; ++outer) {
        int sm = (outer + 1) & 1;
        // ce = c - pi = fma(ss, ninv0, -u*k*v); store ce into k; track max|ce|
        float lm = 0.f;
#pragma unroll
        for (int q = 0; q < 4; ++q)
#pragma unroll
            for (int e = 0; e < 8; ++e) {
                float pi = u[e] * k[q][e] * v[q];
                float ssv = sst[e * 1024 + col0 + q * 64];
                float ce = fmaf(ssv, ninv0, -pi);
                k[q][e] = ce;
                lm = fmaxf(lm, fabsf(ce));
            }
        lm = wmax63(lm);
        if (l == 63) redm[sm][w] = lm;
        __syncthreads();
        float gmx = fmaxf(fmaxf(redm[sm][0], redm[sm][1]),
                          fmaxf(redm[sm][2], redm[sm][3]));
        float scl = -10.f * __builtin_amdgcn_rcpf(gmx + 1e-9f);  // -(1/sden)/LDA
#pragma unroll
        for (int q = 0; q < 4; ++q) {
#pragma unroll
            for (int e = 0; e < 8; ++e) k[q][e] = __expf(k[q][e] * scl);
            v[q] = 1.f;
        }

        for (int it = 0; it < 6; ++it) {          // 5 full (u,v) + final u
            int s = it & 1;
            float p[8];
#pragma unroll
            for (int e = 0; e < 8; ++e) p[e] = 0.f;
#pragma unroll
            for (int q = 0; q < 4; ++q)
#pragma unroll
                for (int e = 0; e < 8; ++e) p[e] = fmaf(k[q][e], v[q], p[e]);
#pragma unroll
            for (int e = 0; e < 8; ++e) p[e] = wsum63(p[e]);
            if (l == 63) {
                *(float4*)&red[s][w][0] = make_float4(p[0], p[1], p[2], p[3]);
                *(float4*)&red[s][w][4] = make_float4(p[4], p[5], p[6], p[7]);
            }
            __syncthreads();
            // combine 4 wave-partials: 8 aligned float4 broadcast loads
            float4 t00 = *(const float4*)&red[s][0][0];
            float4 t01 = *(const float4*)&red[s][0][4];
            float4 t10 = *(const float4*)&red[s][1][0];
            float4 t11 = *(const float4*)&red[s][1][4];
            float4 t20 = *(const float4*)&red[s][2][0];
            float4 t21 = *(const float4*)&red[s][2][4];
            float4 t30 = *(const float4*)&red[s][3][0];
            float4 t31 = *(const float4*)&red[s][3][4];
            float tot0x = (t00.x + t10.x) + (t20.x + t30.x);
            float tot0y = (t00.y + t10.y) + (t20.y + t30.y);
            float tot0z = (t00.z + t10.z) + (t20.z + t30.z);
            float tot0w = (t00.w + t10.w) + (t20.w + t30.w);
            float tot1x = (t01.x + t11.x) + (t21.x + t31.x);
            float tot1y = (t01.y + t11.y) + (t21.y + t31.y);
            float tot1z = (t01.z + t11.z) + (t21.z + t31.z);
            float tot1w = (t01.w + t11.w) + (t21.w + t31.w);
            u[0] = 128.f * __builtin_amdgcn_rcpf(tot0x + 1e-9f);
            u[1] = 128.f * __builtin_amdgcn_rcpf(tot0y + 1e-9f);
            u[2] = 128.f * __builtin_amdgcn_rcpf(tot0z + 1e-9f);
            u[3] = 128.f * __builtin_amdgcn_rcpf(tot0w + 1e-9f);
            u[4] = 128.f * __builtin_amdgcn_rcpf(tot1x + 1e-9f);
            u[5] = 128.f * __builtin_amdgcn_rcpf(tot1y + 1e-9f);
            u[6] = 128.f * __builtin_amdgcn_rcpf(tot1z + 1e-9f);
            u[7] = 128.f * __builtin_amdgcn_rcpf(tot1w + 1e-9f);
            if (it < 5) {
#pragma unroll
                for (int q = 0; q < 4; ++q) {
                    float cs = 0.f;
#pragma unroll
                    for (int e = 0; e < 8; ++e) cs = fmaf(k[q][e], u[e], cs);
                    v[q] = __builtin_amdgcn_rcpf(cs + 1e-9f);
                }
            }
        }
    }

    // ---- epilogue: argmax / gate / select0 / counts / loss ----
    float cnt[8], dp[8];
#pragma unroll
    for (int e = 0; e < 8; ++e) { cnt[e] = 0.f; dp[e] = 0.f; }
#pragma unroll
    for (int q = 0; q < 4; ++q) {
        int col = col0 + q * 64;
        float pv[8];
#pragma unroll
        for (int e = 0; e < 8; ++e) pv[e] = u[e] * k[q][e] * v[q];
        int i = 0; float m = pv[0];
#pragma unroll
        for (int e = 1; e < 8; ++e) { if (pv[e] > m) { m = pv[e]; i = e; } }
        float g = 0.f;
        float se[8];
#pragma unroll
        for (int e = 0; e < 8; ++e) {
            float sv = sst[e * 1024 + col];
            dp[e] += sv;
            if (i == e) g = sv;
        }
#pragma unroll
        for (int e = 0; e < 8; ++e) {
            se[e] = (e == i && g != 0.f) ? 1.f : 0.f;
            cnt[e] += (e == i) ? 1.f : 0.f;
        }
        idx_ws[col] = i;
        gate_ws[col] = g;
        *(float4*)&sel0[col * 8]     = make_float4(se[0], se[1], se[2], se[3]);
        *(float4*)&sel0[col * 8 + 4] = make_float4(se[4], se[5], se[6], se[7]);
    }
#pragma unroll
    for (int e = 0; e < 8; ++e) { cnt[e] = wsum63(cnt[e]); dp[e] = wsum63(dp[e]); }
    if (l == 63) {
#pragma unroll
        for (int e = 0; e < 8; ++e) { cnt_sh[w][e] = cnt[e]; dp_sh[w][e] = dp[e]; }
    }
    __syncthreads();
    if (t == 0) {
        float loss = 0.f;
#pragma unroll
        for (int e = 0; e < 8; ++e) {
            float ce2 = cnt_sh[0][e] + cnt_sh[1][e] + cnt_sh[2][e] + cnt_sh[3][e];
            float de2 = dp_sh[0][e] + dp_sh[1][e] + dp_sh[2][e] + dp_sh[3][e];
            loss += (de2 * (1.f / 1024.f)) * (ce2 * (1.f / 1024.f));
            mcnt_out[e] = ce2;
        }
        loss_out[0] = loss * 8.f;       // mean over 8 * E^2=64 -> sum * 8
    }
}

// ---------------- Kernel C: per-sample fused expert forward ----------------
__global__ __launch_bounds__(256) void expert_kernel(
    const float* __restrict__ x,
    const float* __restrict__ w1g, const float* __restrict__ b1g,
    const float* __restrict__ wdg, const float* __restrict__ bdg,
    const float* __restrict__ wpg, const float* __restrict__ bpg,
    const float* __restrict__ wfg, const float* __restrict__ bfg,
    const int* __restrict__ idx_ws, const float* __restrict__ gate_ws,
    float* __restrict__ out)
{
    __shared__ float xl[3][34][35];
    __shared__ float h1[4][33][33];
    __shared__ float h2[16][16][17];
    __shared__ float w1_l[432];
    __shared__ float wd_l[144];
    __shared__ float wp_l[512];
    __shared__ float wf_l[320];
    __shared__ float b1_l[16], bd_l[16], bp_l[32], bf_l[10];
    __shared__ float poolp[32][9];
    __shared__ float pooled[32];

    int b = blockIdx.x, t = threadIdx.x;
    int e = idx_ws[b];
    float gate = gate_ws[b];

    float* xz = &xl[0][0][0];
    for (int i = t; i < 3 * 34 * 35; i += 256) xz[i] = 0.f;
    for (int i = t; i < 432; i += 256) w1_l[i] = w1g[e * 432 + i];
    if (t < 144) wd_l[t] = wdg[e * 144 + t];
    for (int i = t; i < 512; i += 256) wp_l[i] = wpg[e * 512 + i];
    for (int i = t; i < 320; i += 256) wf_l[i] = wfg[e * 320 + i];
    if (t < 16) b1_l[t] = b1g[e * 16 + t];
    if (t < 16) bd_l[t] = bdg[e * 16 + t];
    if (t < 32) bp_l[t] = bpg[e * 32 + t];
    if (t < 10) bf_l[t] = bfg[e * 10 + t];
    __syncthreads();
    const float* xb = x + b * 3072;
    for (int i = t; i < 3072; i += 256) {
        int c = i >> 10, r = (i >> 5) & 31, j = i & 31;
        xl[c][r + 1][j + 1] = xb[i];
    }
    __syncthreads();

    int ocl = t >> 6;
    int rr = (t >> 1) & 31;
    int jh = t & 1;

    for (int g = 0; g < 4; ++g) {
        int oc = g * 4 + ocl;
        float acc[16];
        float bb = b1_l[oc];
#pragma unroll
        for (int kk = 0; kk < 16; ++kk) acc[kk] = bb;
#pragma unroll
        for (int c = 0; c < 3; ++c) {
#pragma unroll
            for (int di = 0; di < 3; ++di) {
                const float* xr = &xl[c][rr + di][jh * 16];
                float xreg[18];
#pragma unroll
                for (int kk = 0; kk < 18; ++kk) xreg[kk] = xr[kk];
#pragma unroll
                for (int dj = 0; dj < 3; ++dj) {
                    float w = w1_l[oc * 27 + c * 9 + di * 3 + dj];
#pragma unroll
                    for (int kk = 0; kk < 16; ++kk) acc[kk] = fmaf(xreg[kk + dj], w, acc[kk]);
                }
            }
        }
#pragma unroll
        for (int kk = 0; kk < 16; ++kk) h1[ocl][rr][jh * 16 + kk] = relu6f(acc[kk]);
        if (t < 132) { int cc = t / 33, kk = t % 33; h1[cc][32][kk] = 0.f; }
        if (t < 128) { h1[t >> 5][t & 31][32] = 0.f; }
        __syncthreads();
        int i2 = t >> 4, j2 = t & 15;
#pragma unroll
        for (int q = 0; q < 4; ++q) {
            float a = bd_l[g * 4 + q];
#pragma unroll
            for (int di = 0; di < 3; ++di) {
#pragma unroll
                for (int dj = 0; dj < 3; ++dj)
                    a = fmaf(h1[q][2 * i2 + di][2 * j2 + dj],
                             wd_l[(g * 4 + q) * 9 + di * 3 + dj], a);
            }
            h2[g * 4 + q][i2][j2] = relu6f(a);
        }
        __syncthreads();
    }

    int oc2 = t >> 3, part = t & 7;
    float psum = 0.f;
#pragma unroll
    for (int s = 0; s < 32; ++s) {
        int p = part * 32 + s;
        int i = p >> 4, j = p & 15;
        float a = bp_l[oc2];
#pragma unroll
        for (int c = 0; c < 16; ++c) a = fmaf(h2[c][i][j], wp_l[oc2 * 16 + c], a);
        psum += relu6f(a);
    }
    poolp[oc2][part] = psum;
    __syncthreads();
    if (t < 32) {
        float s2 = 0.f;
#pragma unroll
        for (int p2 = 0; p2 < 8; ++p2) s2 += poolp[t][p2];
        pooled[t] = s2 * (1.0f / 256.0f);
    }
    __syncthreads();
    if (t < 10) {
        float o = bf_l[t];
#pragma unroll
        for (int c = 0; c < 32; ++c) o = fmaf(pooled[c], wf_l[t * 32 + c], o);
        out[b * 10 + t] = gate * o;
    }
}

extern "C" void kernel_launch(void* const* d_in, const int* in_sizes, int n_in,
                              void* d_out, int out_size, void* d_ws, size_t ws_size,
                              hipStream_t stream) {
    const float* x  = (const float*)d_in[0];
    const float* rw = (const float*)d_in[1];
    const float* rb = (const float*)d_in[2];
    const float* w1 = (const float*)d_in[3];
    const float* b1 = (const float*)d_in[4];
    const float* wd = (const float*)d_in[5];
    const float* bd = (const float*)d_in[6];
    const float* wp = (const float*)d_in[7];
    const float* bp = (const float*)d_in[8];
    const float* wf = (const float*)d_in[9];
    const float* bf = (const float*)d_in[10];

    float* out  = (float*)d_out;       // [1024*10]
    float* sel0 = out + 10240;         // [1024*8]
    float* loss = out + 18432;         // [1]
    float* mcnt = out + 18433;         // [8]

    float* ws_f = (float*)d_ws;
    float* ss   = ws_f;                 // 8192 floats
    float* gate = ws_f + 8192;          // 1024 floats
    int*   idx  = (int*)(ws_f + 9216);  // 1024 ints

    router_kernel<<<dim3(NB), dim3(256), 0, stream>>>(x, rw, rb, ss);
    solver_kernel<<<dim3(1), dim3(256), 0, stream>>>(ss, gate, idx, sel0, loss, mcnt);
    expert_kernel<<<dim3(NB), dim3(256), 0, stream>>>(x, w1, b1, wd, bd, wp, bp,
                                                      wf, bf, idx, gate, out);
}

// Round 10
// 160.478 us; speedup vs baseline: 1.2461x; 1.0422x over previous
//
#include <hip/hip_runtime.h>

#define NB 1024
#define NE 8

__device__ __forceinline__ float relu6f(float v) { return fminf(fmaxf(v, 0.0f), 6.0f); }

// ---- pure-DPP wave64 reductions (row_ror + row_bcast finisher) ----
// Full 64-lane result valid in lanes 48..63 ONLY (old=0, bound_ctrl=false:
// unselected lanes add identity 0 — safe for sums and max of nonneg).
template <int CTRL>
__device__ __forceinline__ float dpp0(float x) {
    return __builtin_bit_cast(float,
        __builtin_amdgcn_update_dpp(0, __builtin_bit_cast(int, x), CTRL, 0xF, 0xF, false));
}
__device__ __forceinline__ float wsum63(float x) {
    x += dpp0<0x121>(x);   // row_ror:1
    x += dpp0<0x122>(x);   // row_ror:2
    x += dpp0<0x124>(x);   // row_ror:4
    x += dpp0<0x128>(x);   // row_ror:8
    x += dpp0<0x142>(x);   // row_bcast:15
    x += dpp0<0x143>(x);   // row_bcast:31
    return x;
}
__device__ __forceinline__ float wmax63(float x) {   // nonneg inputs only
    x = fmaxf(x, dpp0<0x121>(x));
    x = fmaxf(x, dpp0<0x122>(x));
    x = fmaxf(x, dpp0<0x124>(x));
    x = fmaxf(x, dpp0<0x128>(x));
    x = fmaxf(x, dpp0<0x142>(x));
    x = fmaxf(x, dpp0<0x143>(x));
    return x;
}

// ---------------- Kernel A: router conv + softmax ----------------
__global__ __launch_bounds__(256) void router_kernel(
    const float* __restrict__ x, const float* __restrict__ rw,
    const float* __restrict__ rb, float* __restrict__ ss)
{
    __shared__ float rw_l[384];
    __shared__ float red[4][8];
    int b = blockIdx.x, t = threadIdx.x;
    for (int i = t; i < 384; i += 256) rw_l[i] = rw[i];
    __syncthreads();
    float acc[NE];
#pragma unroll
    for (int e = 0; e < NE; ++e) acc[e] = 0.f;
    const float* xb = x + b * 3072;
    for (int idx = t; idx < 3072; idx += 256) {
        float xv = xb[idx];
        int c = idx >> 10, rem = idx & 1023;
        int i = rem >> 5, j = rem & 31;
        int wb = c * 16 + (i & 3) * 4 + (j & 3);
#pragma unroll
        for (int e = 0; e < NE; ++e) acc[e] += xv * rw_l[e * 48 + wb];
    }
#pragma unroll
    for (int e = 0; e < NE; ++e) acc[e] = wsum63(acc[e]);
    int lane = t & 63, wave = t >> 6;
    if (lane == 63) {
#pragma unroll
        for (int e = 0; e < NE; ++e) red[wave][e] = acc[e];
    }
    __syncthreads();
    if (t == 0) {
        float s[NE], m = -1e30f;
#pragma unroll
        for (int e = 0; e < NE; ++e) {
            s[e] = red[0][e] + red[1][e] + red[2][e] + red[3][e] + rb[e];
            m = fmaxf(m, s[e]);
        }
        float xs = 0.f, ex[NE];
#pragma unroll
        for (int e = 0; e < NE; ++e) { ex[e] = expf(s[e] - m); xs += ex[e]; }
#pragma unroll
        for (int e = 0; e < NE; ++e) ss[b * 8 + e] = ex[e] / xs;
    }
}

// ---------------- Kernel B: OT solver — 4 waves, c in regs, fused passes ---
// R9 analysis: 175 serial reduce->barrier->readback rounds dominate (latency
// floor). This round harvests the remaining issue-side cuts: c[4][8] in regs
// (kills 32 LDS reads/lane/outer; matches reference's once-scaled C rounding),
// p0 fused into exp pass (bit-identical), v-update fused with p-accumulate.
// G_n = I8; G_m == I (off-diag d~5400 -> exp underflows), so C_eff = C - pi.
__global__ __launch_bounds__(256, 2) void solver_kernel(
    const float* __restrict__ ss_g, float* __restrict__ gate_ws,
    int* __restrict__ idx_ws, float* __restrict__ sel0,
    float* __restrict__ loss_out, float* __restrict__ mcnt_out)
{
    __shared__ float sst[8192];                      // ss transposed: [e*1024+col]
    __shared__ __align__(16) float red[2][4][8];     // [parity][wave][e]
    __shared__ float redm[2][4];                     // [parity][wave] max partials
    __shared__ __align__(16) float cnt_sh[4][8], dp_sh[4][8];

    int t = threadIdx.x;
    int l = t & 63, w = t >> 6;

    // stage ss -> transposed LDS, fold global max (ss > 0)
    float mx = 0.f;
    for (int i = t; i < 2048; i += 256) {
        float4 s4 = ((const float4*)ss_g)[i];
        int col = i >> 1, e0 = (i & 1) * 4;
        sst[(e0 + 0) * 1024 + col] = s4.x;
        sst[(e0 + 1) * 1024 + col] = s4.y;
        sst[(e0 + 2) * 1024 + col] = s4.z;
        sst[(e0 + 3) * 1024 + col] = s4.w;
        mx = fmaxf(mx, fmaxf(fmaxf(s4.x, s4.y), fmaxf(s4.z, s4.w)));
    }
    mx = wmax63(mx);
    if (l == 63) redm[0][w] = mx;
    __syncthreads();
    float gm = fmaxf(fmaxf(redm[0][0], redm[0][1]), fmaxf(redm[0][2], redm[0][3]));
    float ninv0 = -__builtin_amdgcn_rcpf(gm + 1e-9f);   // c = ss * ninv0

    // lane state: columns col = w*256 + q*64 + l, q in [0,4)
    int col0 = w * 256 + l;
    float c[4][8], k[4][8], v[4], u[8], p[8];
#pragma unroll
    for (int q = 0; q < 4; ++q) {
        v[q] = 1.f;
#pragma unroll
        for (int e = 0; e < 8; ++e) {
            c[q][e] = sst[e * 1024 + col0 + q * 64] * ninv0;  // once-scaled C (ref rounding)
            k[q][e] = 1.f;
        }
    }
#pragma unroll
    for (int e = 0; e < 8; ++e) u[e] = 0.125f;   // u*k*v == pi0 == 0.125

    for (int outer = 0; outer < 25; ++outer) {
        int sm = (outer + 1) & 1;
        // ce = c - pi (pi = u*k*v); store ce into k; track max|ce|
        float lm = 0.f;
#pragma unroll
        for (int q = 0; q < 4; ++q)
#pragma unroll
            for (int e = 0; e < 8; ++e) {
                float ce = c[q][e] - u[e] * k[q][e] * v[q];
                k[q][e] = ce;
                lm = fmaxf(lm, fabsf(ce));
            }
        lm = wmax63(lm);
        if (l == 63) redm[sm][w] = lm;
        __syncthreads();
        float gmx = fmaxf(fmaxf(redm[sm][0], redm[sm][1]),
                          fmaxf(redm[sm][2], redm[sm][3]));
        float scl = -10.f * __builtin_amdgcn_rcpf(gmx + 1e-9f);  // -(1/sden)/LDA

        // exp pass fused with p0 = K @ v0 (v0 = 1): p0 += k in q order
#pragma unroll
        for (int e = 0; e < 8; ++e) p[e] = 0.f;
#pragma unroll
        for (int q = 0; q < 4; ++q)
#pragma unroll
            for (int e = 0; e < 8; ++e) {
                float kk = __expf(k[q][e] * scl);
                k[q][e] = kk;
                p[e] += kk;
            }

        for (int it = 0; it < 6; ++it) {          // 5 full (u,v) + final u
            int s = it & 1;
#pragma unroll
            for (int e = 0; e < 8; ++e) p[e] = wsum63(p[e]);
            if (l == 63) {
                *(float4*)&red[s][w][0] = make_float4(p[0], p[1], p[2], p[3]);
                *(float4*)&red[s][w][4] = make_float4(p[4], p[5], p[6], p[7]);
            }
            __syncthreads();
            float4 t00 = *(const float4*)&red[s][0][0];
            float4 t01 = *(const float4*)&red[s][0][4];
            float4 t10 = *(const float4*)&red[s][1][0];
            float4 t11 = *(const float4*)&red[s][1][4];
            float4 t20 = *(const float4*)&red[s][2][0];
            float4 t21 = *(const float4*)&red[s][2][4];
            float4 t30 = *(const float4*)&red[s][3][0];
            float4 t31 = *(const float4*)&red[s][3][4];
            u[0] = 128.f * __builtin_amdgcn_rcpf((t00.x + t10.x) + (t20.x + t30.x) + 1e-9f);
            u[1] = 128.f * __builtin_amdgcn_rcpf((t00.y + t10.y) + (t20.y + t30.y) + 1e-9f);
            u[2] = 128.f * __builtin_amdgcn_rcpf((t00.z + t10.z) + (t20.z + t30.z) + 1e-9f);
            u[3] = 128.f * __builtin_amdgcn_rcpf((t00.w + t10.w) + (t20.w + t30.w) + 1e-9f);
            u[4] = 128.f * __builtin_amdgcn_rcpf((t01.x + t11.x) + (t21.x + t31.x) + 1e-9f);
            u[5] = 128.f * __builtin_amdgcn_rcpf((t01.y + t11.y) + (t21.y + t31.y) + 1e-9f);
            u[6] = 128.f * __builtin_amdgcn_rcpf((t01.z + t11.z) + (t21.z + t31.z) + 1e-9f);
            u[7] = 128.f * __builtin_amdgcn_rcpf((t01.w + t11.w) + (t21.w + t31.w) + 1e-9f);
            if (it < 5) {
                // fused: v[q] = 1/(K^T u) then p += k * v (next K @ v)
#pragma unroll
                for (int e = 0; e < 8; ++e) p[e] = 0.f;
#pragma unroll
                for (int q = 0; q < 4; ++q) {
                    float cs = 0.f;
#pragma unroll
                    for (int e = 0; e < 8; ++e) cs = fmaf(k[q][e], u[e], cs);
                    float vq = __builtin_amdgcn_rcpf(cs + 1e-9f);
                    v[q] = vq;
#pragma unroll
                    for (int e = 0; e < 8; ++e) p[e] = fmaf(k[q][e], vq, p[e]);
                }
            }
        }
    }

    // ---- epilogue: argmax / gate / select0 / counts / loss ----
    float cnt[8], dp[8];
#pragma unroll
    for (int e = 0; e < 8; ++e) { cnt[e] = 0.f; dp[e] = 0.f; }
#pragma unroll
    for (int q = 0; q < 4; ++q) {
        int col = col0 + q * 64;
        float pv[8];
#pragma unroll
        for (int e = 0; e < 8; ++e) pv[e] = u[e] * k[q][e] * v[q];
        int i = 0; float m = pv[0];
#pragma unroll
        for (int e = 1; e < 8; ++e) { if (pv[e] > m) { m = pv[e]; i = e; } }
        float g = 0.f;
        float se[8];
#pragma unroll
        for (int e = 0; e < 8; ++e) {
            float sv = sst[e * 1024 + col];
            dp[e] += sv;
            if (i == e) g = sv;
        }
#pragma unroll
        for (int e = 0; e < 8; ++e) {
            se[e] = (e == i && g != 0.f) ? 1.f : 0.f;
            cnt[e] += (e == i) ? 1.f : 0.f;
        }
        idx_ws[col] = i;
        gate_ws[col] = g;
        *(float4*)&sel0[col * 8]     = make_float4(se[0], se[1], se[2], se[3]);
        *(float4*)&sel0[col * 8 + 4] = make_float4(se[4], se[5], se[6], se[7]);
    }
#pragma unroll
    for (int e = 0; e < 8; ++e) { cnt[e] = wsum63(cnt[e]); dp[e] = wsum63(dp[e]); }
    if (l == 63) {
#pragma unroll
        for (int e = 0; e < 8; ++e) { cnt_sh[w][e] = cnt[e]; dp_sh[w][e] = dp[e]; }
    }
    __syncthreads();
    if (t == 0) {
        float loss = 0.f;
#pragma unroll
        for (int e = 0; e < 8; ++e) {
            float ce2 = cnt_sh[0][e] + cnt_sh[1][e] + cnt_sh[2][e] + cnt_sh[3][e];
            float de2 = dp_sh[0][e] + dp_sh[1][e] + dp_sh[2][e] + dp_sh[3][e];
            loss += (de2 * (1.f / 1024.f)) * (ce2 * (1.f / 1024.f));
            mcnt_out[e] = ce2;
        }
        loss_out[0] = loss * 8.f;       // mean over 8 * E^2=64 -> sum * 8
    }
}

// ---------------- Kernel C: per-sample fused expert forward ----------------
// R10: 2 channel-groups of 8 (was 4 of 4) -> 4 barriers (was 8); each thread
// computes 2 conv1 channels reusing one xreg load set (halves conv1 LDS reads).
// LDS ~74KB -> still 2 blocks/CU.
__global__ __launch_bounds__(256, 2) void expert_kernel(
    const float* __restrict__ x,
    const float* __restrict__ w1g, const float* __restrict__ b1g,
    const float* __restrict__ wdg, const float* __restrict__ bdg,
    const float* __restrict__ wpg, const float* __restrict__ bpg,
    const float* __restrict__ wfg, const float* __restrict__ bfg,
    const int* __restrict__ idx_ws, const float* __restrict__ gate_ws,
    float* __restrict__ out)
{
    __shared__ float xl[3][34][35];
    __shared__ float h1[8][33][33];   // 8-channel group; row/col 32 zeroed
    __shared__ float h2[16][16][17];
    __shared__ float w1_l[432];
    __shared__ float wd_l[144];
    __shared__ float wp_l[512];
    __shared__ float wf_l[320];
    __shared__ float b1_l[16], bd_l[16], bp_l[32], bf_l[10];
    __shared__ float poolp[32][9];
    __shared__ float pooled[32];

    int b = blockIdx.x, t = threadIdx.x;
    int e = idx_ws[b];
    float gate = gate_ws[b];

    float* xz = &xl[0][0][0];
    for (int i = t; i < 3 * 34 * 35; i += 256) xz[i] = 0.f;
    for (int i = t; i < 432; i += 256) w1_l[i] = w1g[e * 432 + i];
    if (t < 144) wd_l[t] = wdg[e * 144 + t];
    for (int i = t; i < 512; i += 256) wp_l[i] = wpg[e * 512 + i];
    for (int i = t; i < 320; i += 256) wf_l[i] = wfg[e * 320 + i];
    if (t < 16) b1_l[t] = b1g[e * 16 + t];
    if (t < 16) bd_l[t] = bdg[e * 16 + t];
    if (t < 32) bp_l[t] = bpg[e * 32 + t];
    if (t < 10) bf_l[t] = bfg[e * 10 + t];
    __syncthreads();
    const float* xb = x + b * 3072;
    for (int i = t; i < 3072; i += 256) {
        int c = i >> 10, r = (i >> 5) & 31, j = i & 31;
        xl[c][r + 1][j + 1] = xb[i];
    }
    __syncthreads();

    int ocl = t >> 6;          // wave id 0..3 -> channel pair base
    int rr = (t >> 1) & 31;
    int jh = t & 1;

    for (int g = 0; g < 2; ++g) {
        // conv1 3x3 SAME s1 (+b1, relu6): 2 channels per thread, shared xreg
        int oc0 = g * 8 + ocl * 2;
        float acc[2][16];
#pragma unroll
        for (int kk = 0; kk < 16; ++kk) { acc[0][kk] = b1_l[oc0]; acc[1][kk] = b1_l[oc0 + 1]; }
#pragma unroll
        for (int c = 0; c < 3; ++c) {
#pragma unroll
            for (int di = 0; di < 3; ++di) {
                const float* xr = &xl[c][rr + di][jh * 16];
                float xreg[18];
#pragma unroll
                for (int kk = 0; kk < 18; ++kk) xreg[kk] = xr[kk];
#pragma unroll
                for (int dj = 0; dj < 3; ++dj) {
                    float w0 = w1_l[oc0 * 27 + c * 9 + di * 3 + dj];
                    float w1 = w1_l[(oc0 + 1) * 27 + c * 9 + di * 3 + dj];
#pragma unroll
                    for (int kk = 0; kk < 16; ++kk) {
                        acc[0][kk] = fmaf(xreg[kk + dj], w0, acc[0][kk]);
                        acc[1][kk] = fmaf(xreg[kk + dj], w1, acc[1][kk]);
                    }
                }
            }
        }
        int lc0 = ocl * 2;
#pragma unroll
        for (int kk = 0; kk < 16; ++kk) {
            h1[lc0][rr][jh * 16 + kk]     = relu6f(acc[0][kk]);
            h1[lc0 + 1][rr][jh * 16 + kk] = relu6f(acc[1][kk]);
        }
        // zero SAME-s2 overhang: row 32 (8ch x 33) and col 32 (8ch x 32 rows)
        { int id = t; if (id < 264) { /* covered below */ } }
        if (t < 256) { int cc = t / 33, kk = t % 33; if (cc < 8) h1[cc][32][kk] = 0.f; }
        if (t < 8)   { h1[7][32][t + 25] = 0.f; }              // cells 231+25..263
        h1[t >> 5][t & 31][32] = 0.f;                          // 8ch x 32 rows = 256
        __syncthreads();
        // depthwise 3x3 stride2 SAME (pad lo=0 hi=1), +bd, relu6: 8 ch/thread
        int i2 = t >> 4, j2 = t & 15;
#pragma unroll
        for (int q = 0; q < 8; ++q) {
            float a = bd_l[g * 8 + q];
#pragma unroll
            for (int di = 0; di < 3; ++di) {
#pragma unroll
                for (int dj = 0; dj < 3; ++dj)
                    a = fmaf(h1[q][2 * i2 + di][2 * j2 + dj],
                             wd_l[(g * 8 + q) * 9 + di * 3 + dj], a);
            }
            h2[g * 8 + q][i2][j2] = relu6f(a);
        }
        __syncthreads();
    }

    // pointwise 16->32 (+bp, relu6) fused with spatial mean
    int oc2 = t >> 3, part = t & 7;
    float psum = 0.f;
#pragma unroll
    for (int s = 0; s < 32; ++s) {
        int p = part * 32 + s;
        int i = p >> 4, j = p & 15;
        float a = bp_l[oc2];
#pragma unroll
        for (int c = 0; c < 16; ++c) a = fmaf(h2[c][i][j], wp_l[oc2 * 16 + c], a);
        psum += relu6f(a);
    }
    poolp[oc2][part] = psum;
    __syncthreads();
    if (t < 32) {
        float s2 = 0.f;
#pragma unroll
        for (int p2 = 0; p2 < 8; ++p2) s2 += poolp[t][p2];
        pooled[t] = s2 * (1.0f / 256.0f);
    }
    __syncthreads();
    if (t < 10) {
        float o = bf_l[t];
#pragma unroll
        for (int c = 0; c < 32; ++c) o = fmaf(pooled[c], wf_l[t * 32 + c], o);
        out[b * 10 + t] = gate * o;
    }
}

extern "C" void kernel_launch(void* const* d_in, const int* in_sizes, int n_in,
                              void* d_out, int out_size, void* d_ws, size_t ws_size,
                              hipStream_t stream) {
    const float* x  = (const float*)d_in[0];
    const float* rw = (const float*)d_in[1];
    const float* rb = (const float*)d_in[2];
    const float* w1 = (const float*)d_in[3];
    const float* b1 = (const float*)d_in[4];
    const float* wd = (const float*)d_in[5];
    const float* bd = (const float*)d_in[6];
    const float* wp = (const float*)d_in[7];
    const float* bp = (const float*)d_in[8];
    const float* wf = (const float*)d_in[9];
    const float* bf = (const float*)d_in[10];

    float* out  = (float*)d_out;       // [1024*10]
    float* sel0 = out + 10240;         // [1024*8]
    float* loss = out + 18432;         // [1]
    float* mcnt = out + 18433;         // [8]

    float* ws_f = (float*)d_ws;
    float* ss   = ws_f;                 // 8192 floats
    float* gate = ws_f + 8192;          // 1024 floats
    int*   idx  = (int*)(ws_f + 9216);  // 1024 ints

    router_kernel<<<dim3(NB), dim3(256), 0, stream>>>(x, rw, rb, ss);
    solver_kernel<<<dim3(1), dim3(256), 0, stream>>>(ss, gate, idx, sel0, loss, mcnt);
    expert_kernel<<<dim3(NB), dim3(256), 0, stream>>>(x, w1, b1, wd, bd, wp, bp,
                                                      wf, bf, idx, gate, out);
}

// Round 11
// 137.758 us; speedup vs baseline: 1.4516x; 1.1649x over previous
//
#include <hip/hip_runtime.h>

#define NB 1024
#define NE 8

__device__ __forceinline__ float relu6f(float v) { return fminf(fmaxf(v, 0.0f), 6.0f); }

// ---- pure-DPP wave64 reductions ----
// Generic (builtin) forms for cold paths: full result valid in lanes 48..63.
template <int CTRL>
__device__ __forceinline__ float dpp0(float x) {
    return __builtin_bit_cast(float,
        __builtin_amdgcn_update_dpp(0, __builtin_bit_cast(int, x), CTRL, 0xF, 0xF, false));
}
__device__ __forceinline__ float wsum63(float x) {
    x += dpp0<0x121>(x);   // row_ror:1
    x += dpp0<0x122>(x);   // row_ror:2
    x += dpp0<0x124>(x);   // row_ror:4
    x += dpp0<0x128>(x);   // row_ror:8
    x += dpp0<0x142>(x);   // row_bcast:15
    x += dpp0<0x143>(x);   // row_bcast:31
    return x;
}
__device__ __forceinline__ float wmax63(float x) {   // nonneg inputs only
    x = fmaxf(x, dpp0<0x121>(x));
    x = fmaxf(x, dpp0<0x122>(x));
    x = fmaxf(x, dpp0<0x124>(x));
    x = fmaxf(x, dpp0<0x128>(x));
    x = fmaxf(x, dpp0<0x142>(x));
    x = fmaxf(x, dpp0<0x143>(x));
    return x;
}

// HOT PATH: 8-value wave64 sum via FUSED v_add_f32_dpp (1 instr/stage vs the
// builtin's mov-zero + mov_dpp + add). Stage-major interleave of the 8
// independent chains puts dependent ops 8 instrs apart -> DPP read-after-VALU
// hazard (2 wait states) satisfied without s_nop; one s_nop 1 guards entry.
// Bit-identical adds/order to wsum63. Result valid in lanes 48..63.
#define DPP_ROW(OPND, CTRL) \
    "v_add_f32_dpp " OPND ", " OPND ", " OPND " " CTRL \
    " row_mask:0xf bank_mask:0xf bound_ctrl:0\n\t"
#define DPP_STAGE(CTRL) \
    DPP_ROW("%0", CTRL) DPP_ROW("%1", CTRL) DPP_ROW("%2", CTRL) DPP_ROW("%3", CTRL) \
    DPP_ROW("%4", CTRL) DPP_ROW("%5", CTRL) DPP_ROW("%6", CTRL) DPP_ROW("%7", CTRL)

__device__ __forceinline__ void wsum63x8(float p[8]) {
    asm volatile(
        "s_nop 1\n\t"
        DPP_STAGE("row_ror:1")
        DPP_STAGE("row_ror:2")
        DPP_STAGE("row_ror:4")
        DPP_STAGE("row_ror:8")
        DPP_STAGE("row_bcast:15")
        DPP_STAGE("row_bcast:31")
        : "+v"(p[0]), "+v"(p[1]), "+v"(p[2]), "+v"(p[3]),
          "+v"(p[4]), "+v"(p[5]), "+v"(p[6]), "+v"(p[7]));
}

// ---------------- Kernel A: router conv + softmax ----------------
__global__ __launch_bounds__(256) void router_kernel(
    const float* __restrict__ x, const float* __restrict__ rw,
    const float* __restrict__ rb, float* __restrict__ ss)
{
    __shared__ float rw_l[384];
    __shared__ float red[4][8];
    int b = blockIdx.x, t = threadIdx.x;
    for (int i = t; i < 384; i += 256) rw_l[i] = rw[i];
    __syncthreads();
    float acc[NE];
#pragma unroll
    for (int e = 0; e < NE; ++e) acc[e] = 0.f;
    const float* xb = x + b * 3072;
    for (int idx = t; idx < 3072; idx += 256) {
        float xv = xb[idx];
        int c = idx >> 10, rem = idx & 1023;
        int i = rem >> 5, j = rem & 31;
        int wb = c * 16 + (i & 3) * 4 + (j & 3);
#pragma unroll
        for (int e = 0; e < NE; ++e) acc[e] += xv * rw_l[e * 48 + wb];
    }
    wsum63x8(acc);
    int lane = t & 63, wave = t >> 6;
    if (lane == 63) {
#pragma unroll
        for (int e = 0; e < NE; ++e) red[wave][e] = acc[e];
    }
    __syncthreads();
    if (t == 0) {
        float s[NE], m = -1e30f;
#pragma unroll
        for (int e = 0; e < NE; ++e) {
            s[e] = red[0][e] + red[1][e] + red[2][e] + red[3][e] + rb[e];
            m = fmaxf(m, s[e]);
        }
        float xs = 0.f, ex[NE];
#pragma unroll
        for (int e = 0; e < NE; ++e) { ex[e] = expf(s[e] - m); xs += ex[e]; }
#pragma unroll
        for (int e = 0; e < NE; ++e) ss[b * 8 + e] = ex[e] / xs;
    }
}

// ---------------- Kernel B: OT solver — 4 waves, fused-DPP reduce ----------
// G_n = I8; G_m == I (off-diag d~5400 -> exp underflows), so C_eff = C - pi.
__global__ __launch_bounds__(256, 2) void solver_kernel(
    const float* __restrict__ ss_g, float* __restrict__ gate_ws,
    int* __restrict__ idx_ws, float* __restrict__ sel0,
    float* __restrict__ loss_out, float* __restrict__ mcnt_out)
{
    __shared__ float sst[8192];                      // ss transposed: [e*1024+col]
    __shared__ __align__(16) float red[2][4][8];     // [parity][wave][e]
    __shared__ float redm[2][4];                     // [parity][wave] max partials
    __shared__ __align__(16) float cnt_sh[4][8], dp_sh[4][8];

    int t = threadIdx.x;
    int l = t & 63, w = t >> 6;

    // stage ss -> transposed LDS, fold global max (ss > 0)
    float mx = 0.f;
    for (int i = t; i < 2048; i += 256) {
        float4 s4 = ((const float4*)ss_g)[i];
        int col = i >> 1, e0 = (i & 1) * 4;
        sst[(e0 + 0) * 1024 + col] = s4.x;
        sst[(e0 + 1) * 1024 + col] = s4.y;
        sst[(e0 + 2) * 1024 + col] = s4.z;
        sst[(e0 + 3) * 1024 + col] = s4.w;
        mx = fmaxf(mx, fmaxf(fmaxf(s4.x, s4.y), fmaxf(s4.z, s4.w)));
    }
    mx = wmax63(mx);
    if (l == 63) redm[0][w] = mx;
    __syncthreads();
    float gm = fmaxf(fmaxf(redm[0][0], redm[0][1]), fmaxf(redm[0][2], redm[0][3]));
    float ninv0 = -__builtin_amdgcn_rcpf(gm + 1e-9f);   // c = ss * ninv0

    // lane state: columns col = w*256 + q*64 + l, q in [0,4)
    int col0 = w * 256 + l;
    float c[4][8], k[4][8], v[4], u[8], p[8];
#pragma unroll
    for (int q = 0; q < 4; ++q) {
        v[q] = 1.f;
#pragma unroll
        for (int e = 0; e < 8; ++e) {
            c[q][e] = sst[e * 1024 + col0 + q * 64] * ninv0;  // once-scaled C
            k[q][e] = 1.f;
        }
    }
#pragma unroll
    for (int e = 0; e < 8; ++e) u[e] = 0.125f;   // u*k*v == pi0 == 0.125

    for (int outer = 0; outer < 25; ++outer) {
        int sm = (outer + 1) & 1;
        // ce = c - pi (pi = u*k*v); store ce into k; track max|ce|
        float lm = 0.f;
#pragma unroll
        for (int q = 0; q < 4; ++q)
#pragma unroll
            for (int e = 0; e < 8; ++e) {
                float ce = c[q][e] - u[e] * k[q][e] * v[q];
                k[q][e] = ce;
                lm = fmaxf(lm, fabsf(ce));
            }
        lm = wmax63(lm);
        if (l == 63) redm[sm][w] = lm;
        __syncthreads();
        float gmx = fmaxf(fmaxf(redm[sm][0], redm[sm][1]),
                          fmaxf(redm[sm][2], redm[sm][3]));
        float scl = -10.f * __builtin_amdgcn_rcpf(gmx + 1e-9f);  // -(1/sden)/LDA

        // exp pass fused with p0 = K @ v0 (v0 = 1)
#pragma unroll
        for (int e = 0; e < 8; ++e) p[e] = 0.f;
#pragma unroll
        for (int q = 0; q < 4; ++q)
#pragma unroll
            for (int e = 0; e < 8; ++e) {
                float kk = __expf(k[q][e] * scl);
                k[q][e] = kk;
                p[e] += kk;
            }

        for (int it = 0; it < 6; ++it) {          // 5 full (u,v) + final u
            int s = it & 1;
            wsum63x8(p);                          // fused-DPP 8-value reduce
            if (l == 63) {
                *(float4*)&red[s][w][0] = make_float4(p[0], p[1], p[2], p[3]);
                *(float4*)&red[s][w][4] = make_float4(p[4], p[5], p[6], p[7]);
            }
            __syncthreads();
            float4 t00 = *(const float4*)&red[s][0][0];
            float4 t01 = *(const float4*)&red[s][0][4];
            float4 t10 = *(const float4*)&red[s][1][0];
            float4 t11 = *(const float4*)&red[s][1][4];
            float4 t20 = *(const float4*)&red[s][2][0];
            float4 t21 = *(const float4*)&red[s][2][4];
            float4 t30 = *(const float4*)&red[s][3][0];
            float4 t31 = *(const float4*)&red[s][3][4];
            u[0] = 128.f * __builtin_amdgcn_rcpf((t00.x + t10.x) + (t20.x + t30.x) + 1e-9f);
            u[1] = 128.f * __builtin_amdgcn_rcpf((t00.y + t10.y) + (t20.y + t30.y) + 1e-9f);
            u[2] = 128.f * __builtin_amdgcn_rcpf((t00.z + t10.z) + (t20.z + t30.z) + 1e-9f);
            u[3] = 128.f * __builtin_amdgcn_rcpf((t00.w + t10.w) + (t20.w + t30.w) + 1e-9f);
            u[4] = 128.f * __builtin_amdgcn_rcpf((t01.x + t11.x) + (t21.x + t31.x) + 1e-9f);
            u[5] = 128.f * __builtin_amdgcn_rcpf((t01.y + t11.y) + (t21.y + t31.y) + 1e-9f);
            u[6] = 128.f * __builtin_amdgcn_rcpf((t01.z + t11.z) + (t21.z + t31.z) + 1e-9f);
            u[7] = 128.f * __builtin_amdgcn_rcpf((t01.w + t11.w) + (t21.w + t31.w) + 1e-9f);
            if (it < 5) {
                // fused: v[q] = 1/(K^T u) then p += k * v (next K @ v)
#pragma unroll
                for (int e = 0; e < 8; ++e) p[e] = 0.f;
#pragma unroll
                for (int q = 0; q < 4; ++q) {
                    float cs = 0.f;
#pragma unroll
                    for (int e = 0; e < 8; ++e) cs = fmaf(k[q][e], u[e], cs);
                    float vq = __builtin_amdgcn_rcpf(cs + 1e-9f);
                    v[q] = vq;
#pragma unroll
                    for (int e = 0; e < 8; ++e) p[e] = fmaf(k[q][e], vq, p[e]);
                }
            }
        }
    }

    // ---- epilogue: argmax / gate / select0 / counts / loss ----
    float cnt[8], dp[8];
#pragma unroll
    for (int e = 0; e < 8; ++e) { cnt[e] = 0.f; dp[e] = 0.f; }
#pragma unroll
    for (int q = 0; q < 4; ++q) {
        int col = col0 + q * 64;
        float pv[8];
#pragma unroll
        for (int e = 0; e < 8; ++e) pv[e] = u[e] * k[q][e] * v[q];
        int i = 0; float m = pv[0];
#pragma unroll
        for (int e = 1; e < 8; ++e) { if (pv[e] > m) { m = pv[e]; i = e; } }
        float g = 0.f;
        float se[8];
#pragma unroll
        for (int e = 0; e < 8; ++e) {
            float sv = sst[e * 1024 + col];
            dp[e] += sv;
            if (i == e) g = sv;
        }
#pragma unroll
        for (int e = 0; e < 8; ++e) {
            se[e] = (e == i && g != 0.f) ? 1.f : 0.f;
            cnt[e] += (e == i) ? 1.f : 0.f;
        }
        idx_ws[col] = i;
        gate_ws[col] = g;
        *(float4*)&sel0[col * 8]     = make_float4(se[0], se[1], se[2], se[3]);
        *(float4*)&sel0[col * 8 + 4] = make_float4(se[4], se[5], se[6], se[7]);
    }
#pragma unroll
    for (int e = 0; e < 8; ++e) { cnt[e] = wsum63(cnt[e]); dp[e] = wsum63(dp[e]); }
    if (l == 63) {
#pragma unroll
        for (int e = 0; e < 8; ++e) { cnt_sh[w][e] = cnt[e]; dp_sh[w][e] = dp[e]; }
    }
    __syncthreads();
    if (t == 0) {
        float loss = 0.f;
#pragma unroll
        for (int e = 0; e < 8; ++e) {
            float ce2 = cnt_sh[0][e] + cnt_sh[1][e] + cnt_sh[2][e] + cnt_sh[3][e];
            float de2 = dp_sh[0][e] + dp_sh[1][e] + dp_sh[2][e] + dp_sh[3][e];
            loss += (de2 * (1.f / 1024.f)) * (ce2 * (1.f / 1024.f));
            mcnt_out[e] = ce2;
        }
        loss_out[0] = loss * 8.f;       // mean over 8 * E^2=64 -> sum * 8
    }
}

// ---------------- Kernel C: per-sample fused expert forward ----------------
__global__ __launch_bounds__(256, 2) void expert_kernel(
    const float* __restrict__ x,
    const float* __restrict__ w1g, const float* __restrict__ b1g,
    const float* __restrict__ wdg, const float* __restrict__ bdg,
    const float* __restrict__ wpg, const float* __restrict__ bpg,
    const float* __restrict__ wfg, const float* __restrict__ bfg,
    const int* __restrict__ idx_ws, const float* __restrict__ gate_ws,
    float* __restrict__ out)
{
    __shared__ float xl[3][34][35];
    __shared__ float h1[8][33][33];   // 8-channel group; row/col 32 zeroed
    __shared__ float h2[16][16][17];
    __shared__ float w1_l[432];
    __shared__ float wd_l[144];
    __shared__ float wp_l[512];
    __shared__ float wf_l[320];
    __shared__ float b1_l[16], bd_l[16], bp_l[32], bf_l[10];
    __shared__ float poolp[32][9];
    __shared__ float pooled[32];

    int b = blockIdx.x, t = threadIdx.x;
    int e = idx_ws[b];
    float gate = gate_ws[b];

    float* xz = &xl[0][0][0];
    for (int i = t; i < 3 * 34 * 35; i += 256) xz[i] = 0.f;
    for (int i = t; i < 432; i += 256) w1_l[i] = w1g[e * 432 + i];
    if (t < 144) wd_l[t] = wdg[e * 144 + t];
    for (int i = t; i < 512; i += 256) wp_l[i] = wpg[e * 512 + i];
    for (int i = t; i < 320; i += 256) wf_l[i] = wfg[e * 320 + i];
    if (t < 16) b1_l[t] = b1g[e * 16 + t];
    if (t < 16) bd_l[t] = bdg[e * 16 + t];
    if (t < 32) bp_l[t] = bpg[e * 32 + t];
    if (t < 10) bf_l[t] = bfg[e * 10 + t];
    __syncthreads();
    const float* xb = x + b * 3072;
    for (int i = t; i < 3072; i += 256) {
        int c = i >> 10, r = (i >> 5) & 31, j = i & 31;
        xl[c][r + 1][j + 1] = xb[i];
    }
    __syncthreads();

    int ocl = t >> 6;          // wave id 0..3 -> channel pair base
    int rr = (t >> 1) & 31;
    int jh = t & 1;

    for (int g = 0; g < 2; ++g) {
        // conv1 3x3 SAME s1 (+b1, relu6): 2 channels per thread, shared xreg
        int oc0 = g * 8 + ocl * 2;
        float acc[2][16];
#pragma unroll
        for (int kk = 0; kk < 16; ++kk) { acc[0][kk] = b1_l[oc0]; acc[1][kk] = b1_l[oc0 + 1]; }
#pragma unroll
        for (int c = 0; c < 3; ++c) {
#pragma unroll
            for (int di = 0; di < 3; ++di) {
                const float* xr = &xl[c][rr + di][jh * 16];
                float xreg[18];
#pragma unroll
                for (int kk = 0; kk < 18; ++kk) xreg[kk] = xr[kk];
#pragma unroll
                for (int dj = 0; dj < 3; ++dj) {
                    float w0 = w1_l[oc0 * 27 + c * 9 + di * 3 + dj];
                    float w1 = w1_l[(oc0 + 1) * 27 + c * 9 + di * 3 + dj];
#pragma unroll
                    for (int kk = 0; kk < 16; ++kk) {
                        acc[0][kk] = fmaf(xreg[kk + dj], w0, acc[0][kk]);
                        acc[1][kk] = fmaf(xreg[kk + dj], w1, acc[1][kk]);
                    }
                }
            }
        }
        int lc0 = ocl * 2;
#pragma unroll
        for (int kk = 0; kk < 16; ++kk) {
            h1[lc0][rr][jh * 16 + kk]     = relu6f(acc[0][kk]);
            h1[lc0 + 1][rr][jh * 16 + kk] = relu6f(acc[1][kk]);
        }
        // zero SAME-s2 overhang: row 32 (8ch x 33) and col 32 (8ch x 32 rows)
        if (t < 256) { int cc = t / 33, kk = t % 33; if (cc < 8) h1[cc][32][kk] = 0.f; }
        if (t < 8)   { h1[7][32][t + 25] = 0.f; }
        h1[t >> 5][t & 31][32] = 0.f;
        __syncthreads();
        // depthwise 3x3 stride2 SAME (pad lo=0 hi=1), +bd, relu6: 8 ch/thread
        int i2 = t >> 4, j2 = t & 15;
#pragma unroll
        for (int q = 0; q < 8; ++q) {
            float a = bd_l[g * 8 + q];
#pragma unroll
            for (int di = 0; di < 3; ++di) {
#pragma unroll
                for (int dj = 0; dj < 3; ++dj)
                    a = fmaf(h1[q][2 * i2 + di][2 * j2 + dj],
                             wd_l[(g * 8 + q) * 9 + di * 3 + dj], a);
            }
            h2[g * 8 + q][i2][j2] = relu6f(a);
        }
        __syncthreads();
    }

    // pointwise 16->32 (+bp, relu6) fused with spatial mean
    int oc2 = t >> 3, part = t & 7;
    float psum = 0.f;
#pragma unroll
    for (int s = 0; s < 32; ++s) {
        int p = part * 32 + s;
        int i = p >> 4, j = p & 15;
        float a = bp_l[oc2];
#pragma unroll
        for (int c = 0; c < 16; ++c) a = fmaf(h2[c][i][j], wp_l[oc2 * 16 + c], a);
        psum += relu6f(a);
    }
    poolp[oc2][part] = psum;
    __syncthreads();
    if (t < 32) {
        float s2 = 0.f;
#pragma unroll
        for (int p2 = 0; p2 < 8; ++p2) s2 += poolp[t][p2];
        pooled[t] = s2 * (1.0f / 256.0f);
    }
    __syncthreads();
    if (t < 10) {
        float o = bf_l[t];
#pragma unroll
        for (int c = 0; c < 32; ++c) o = fmaf(pooled[c], wf_l[t * 32 + c], o);
        out[b * 10 + t] = gate * o;
    }
}

extern "C" void kernel_launch(void* const* d_in, const int* in_sizes, int n_in,
                              void* d_out, int out_size, void* d_ws, size_t ws_size,
                              hipStream_t stream) {
    const float* x  = (const float*)d_in[0];
    const float* rw = (const float*)d_in[1];
    const float* rb = (const float*)d_in[2];
    const float* w1 = (const float*)d_in[3];
    const float* b1 = (const float*)d_in[4];
    const float* wd = (const float*)d_in[5];
    const float* bd = (const float*)d_in[6];
    const float* wp = (const float*)d_in[7];
    const float* bp = (const float*)d_in[8];
    const float* wf = (const float*)d_in[9];
    const float* bf = (const float*)d_in[10];

    float* out  = (float*)d_out;       // [1024*10]
    float* sel0 = out + 10240;         // [1024*8]
    float* loss = out + 18432;         // [1]
    float* mcnt = out + 18433;         // [8]

    float* ws_f = (float*)d_ws;
    float* ss   = ws_f;                 // 8192 floats
    float* gate = ws_f + 8192;          // 1024 floats
    int*   idx  = (int*)(ws_f + 9216);  // 1024 ints

    router_kernel<<<dim3(NB), dim3(256), 0, stream>>>(x, rw, rb, ss);
    solver_kernel<<<dim3(1), dim3(256), 0, stream>>>(ss, gate, idx, sel0, loss, mcnt);
    expert_kernel<<<dim3(NB), dim3(256), 0, stream>>>(x, w1, b1, wd, bd, wp, bp,
                                                      wf, bf, idx, gate, out);
}